// Round 18
// baseline (77.776 us; speedup 1.0000x reference)
//
#include <hip/hip_runtime.h>
#include <hip/hip_bf16.h>

#define N_TOK 32768
#define H 128
#define I_DIM 512
#define E 8
#define EPS 1e-5f
#define GATE_TPB 128
#define NSLOT_MAX (N_TOK * 2 + E * 32)   // 32-padded slot capacity (65792)

typedef __attribute__((ext_vector_type(8))) short short8;
typedef __attribute__((ext_vector_type(4))) float f32x4;
typedef __attribute__((ext_vector_type(2))) unsigned int u32x2;
typedef __attribute__((ext_vector_type(4))) unsigned int u32x4;
typedef __attribute__((ext_vector_type(8))) __bf16 bf16x8;

__device__ inline unsigned short f2bf(float f){
  unsigned int u = __builtin_bit_cast(unsigned int, f);
  u += 0x7fffu + ((u >> 16) & 1u);
  return (unsigned short)(u >> 16);
}
__device__ inline float bf2f(unsigned short s){
  unsigned int u = ((unsigned int)s) << 16;
  return __builtin_bit_cast(float, u);
}
// Packed f32->bf16 (RNE) via HIP intrinsic; byte-copy out.
__device__ inline unsigned int cvtpk(float lo, float hi){
  __hip_bfloat162 h = __float22bfloat162_rn(make_float2(lo, hi));
  unsigned int r;
  __builtin_memcpy(&r, &h, 4);
  return r;
}
// fast GELU (tanh form), |err| <= ~3e-4 vs exact erf-GELU
__device__ inline float gelu_fast(float x){
  const float A = 0.10294517f;
  const float B = 2.30214175f;
  float x2 = x * x;
  float v  = __builtin_fmaf(x2, A, B);
  float z  = __builtin_amdgcn_exp2f(v * x);
  float r  = __builtin_amdgcn_rcpf(z + 1.f);
  return __builtin_fmaf(-x, r, x);
}
__device__ inline f32x4 mfma16(short8 a, short8 b, f32x4 c){
  return __builtin_amdgcn_mfma_f32_16x16x32_bf16(
      __builtin_bit_cast(bf16x8, a), __builtin_bit_cast(bf16x8, b), c, 0, 0, 0);
}

// Dense 32-padded slot-space -> (expert, base, ne).
__device__ inline int slot_to_expert(const int* __restrict__ cnt, int slot0,
                                     int& base, int& ne){
  int e = -1, p = 0;
  #pragma unroll
  for (int q = 0; q < E; ++q){
    int c = cnt[q];
    int pc = (c + 31) & ~31;
    if (slot0 >= p && slot0 < p + pc){ e = q; base = slot0 - p; ne = c; }
    p += pc;
  }
  return e;
}

// ---------------- Kernel FRONT: prep (blk 0-255) | gate (256-511) | zero ----
// Gate now also produces a1 = gelu(ln1(xn)) per (token, expert) assignment
// directly into a1buf[(e,pos)][128] bf16 — k_mlp's phase-1 (and 2 of its 4
// barriers) disappear. Token xn rows live in gate-block LDS (XOR-swizzled),
// so the global xn buffer is gone.
__global__ __launch_bounds__(256) void k_front(
    const float* __restrict__ w1, const float* __restrict__ w2,
    unsigned short* __restrict__ w1p, unsigned short* __restrict__ w2p,
    const float* __restrict__ x, const float* __restrict__ gw,
    const float* __restrict__ gb,
    const float* __restrict__ ln1g, const float* __restrict__ ln1b,
    unsigned short* __restrict__ a1buf,
    int* __restrict__ cnt, int* __restrict__ list, float* __restrict__ score,
    float* __restrict__ out){
  __shared__ __align__(16) float gws[E * H];       // 4 KB
  __shared__ __align__(16) float g1s[E * H];       // 4 KB
  __shared__ __align__(16) float b1s[E * H];       // 4 KB
  __shared__ __align__(16) unsigned short xnl[GATE_TPB * H];  // 32 KB, swizzled
  __shared__ float gbs[E];
  __shared__ int   lcnt[E];
  __shared__ int   gbase[E];
  __shared__ int   te[2][GATE_TPB];
  __shared__ float tsc[2][GATE_TPB];
  __shared__ int   tlp[2][GATE_TPB];

  int tid = threadIdx.x;
  int blk = blockIdx.x;

  if (blk >= 512){
    float4 z = {0.f, 0.f, 0.f, 0.f};
    float4* o4 = (float4*)out;
    int base4 = (blk - 512) * 2048 + tid;
    #pragma unroll
    for (int q = 0; q < 8; ++q) o4[base4 + q * 256] = z;
    return;
  }

  if (blk < 256){
    int q = blk * 256 + tid;
    int e = q >> 13, rem = q & 8191;
    {
      int it = rem >> 8, kt = (rem >> 6) & 3, l = rem & 63;
      int row = it * 16 + (l & 15), h0 = kt * 32 + (l >> 4) * 8;
      const float* src = w1 + ((size_t)(e * 512 + row) * 128 + h0);
      float4 v0 = *(const float4*)src, v1 = *(const float4*)(src + 4);
      short8 o;
      #pragma unroll
      for (int j = 0; j < 4; ++j){ o[j] = (short)f2bf(v0[j]); o[j+4] = (short)f2bf(v1[j]); }
      *(short8*)(w1p + (size_t)q * 8) = o;
    }
    {
      int ht = rem >> 10, kt = (rem >> 6) & 15, l = rem & 63;
      int row = ht * 16 + (l & 15), i0 = kt * 32 + (l >> 4) * 8;
      const float* src = w2 + ((size_t)(e * 128 + row) * 512 + i0);
      float4 v0 = *(const float4*)src, v1 = *(const float4*)(src + 4);
      short8 o;
      #pragma unroll
      for (int j = 0; j < 4; ++j){ o[j] = (short)f2bf(v0[j]); o[j+4] = (short)f2bf(v1[j]); }
      *(short8*)(w2p + (size_t)q * 8) = o;
    }
    return;
  }

  // ---- gate ----
  for (int i = tid; i < E * H; i += 256){
    gws[i] = gw[i]; g1s[i] = ln1g[i]; b1s[i] = ln1b[i];
  }
  if (tid < E){ gbs[tid] = gb[tid]; lcnt[tid] = 0; }
  __syncthreads();

  int wave = tid >> 6, lane = tid & 63;
  int g = lane >> 3, c8 = lane & 7;
  int tok0 = (blk - 256) * GATE_TPB;
  const float4* gws4 = (const float4*)gws;

  for (int t = 0; t < 4; ++t){
    int lt = t * 32 + wave * 8 + g;
    int tok = tok0 + lt;
    const float4* xr = (const float4*)(x + (size_t)tok * H) + c8 * 4;
    float4 v[4];
    #pragma unroll
    for (int q = 0; q < 4; ++q) v[q] = xr[q];

    float S = 0.f, Q = 0.f;
    float lg[E];
    #pragma unroll
    for (int e = 0; e < E; e++) lg[e] = 0.f;
    #pragma unroll
    for (int q = 0; q < 4; ++q){
      #pragma unroll
      for (int r = 0; r < 4; ++r){
        float f = v[q][r];
        S += f; Q = __builtin_fmaf(f, f, Q);
      }
      #pragma unroll
      for (int e = 0; e < E; e++){
        float4 wv = gws4[e * 32 + c8 * 4 + q];
        #pragma unroll
        for (int r = 0; r < 4; ++r) lg[e] = __builtin_fmaf(v[q][r], wv[r], lg[e]);
      }
    }
    #pragma unroll
    for (int m = 1; m < 8; m <<= 1){
      S += __shfl_xor(S, m);
      Q += __shfl_xor(Q, m);
      #pragma unroll
      for (int e = 0; e < E; e++) lg[e] += __shfl_xor(lg[e], m);
    }

    float mu = S * (1.f / H);
    float var = Q * (1.f / H) - mu * mu;
    float rsig = rsqrtf(fmaxf(var, 0.f) + EPS);

    short8 s0, s1;
    #pragma unroll
    for (int r = 0; r < 4; ++r){
      s0[r]     = (short)f2bf((v[0][r] - mu) * rsig);
      s0[r + 4] = (short)f2bf((v[1][r] - mu) * rsig);
      s1[r]     = (short)f2bf((v[2][r] - mu) * rsig);
      s1[r + 4] = (short)f2bf((v[3][r] - mu) * rsig);
    }
    // xn row -> LDS, XOR-swizzled (write-out reads rows column-sliced)
    int swz = (lt & 7) << 4;
    char* xrow = (char*)xnl + lt * 256;
    *(short8*)(xrow + ((c8 * 32) ^ swz))      = s0;
    *(short8*)(xrow + ((c8 * 32 + 16) ^ swz)) = s1;

    if (c8 == 0){
      float mx = -1e30f;
      #pragma unroll
      for (int e = 0; e < E; e++){ lg[e] += gbs[e]; mx = fmaxf(mx, lg[e]); }
      float p[E], sum = 0.f;
      #pragma unroll
      for (int e = 0; e < E; e++){ p[e] = __expf(lg[e] - mx); sum += p[e]; }
      float inv = 1.f / sum;
      int e0 = 0; float p0 = p[0];
      #pragma unroll
      for (int e = 1; e < E; e++) if (p[e] > p0){ e0 = e; p0 = p[e]; }
      int e1 = -1; float p1 = -1.f;
      #pragma unroll
      for (int e = 0; e < E; e++) if (e != e0 && p[e] > p1){ e1 = e; p1 = p[e]; }
      te[0][lt] = e0; tsc[0][lt] = p0 * inv; tlp[0][lt] = atomicAdd(&lcnt[e0], 1);
      te[1][lt] = e1; tsc[1][lt] = p1 * inv; tlp[1][lt] = atomicAdd(&lcnt[e1], 1);
    }
  }
  __syncthreads();
  if (tid < E) gbase[tid] = atomicAdd(&cnt[tid], lcnt[tid]);
  __syncthreads();

  // ---- write-out: list/score + a1 rows (thread = (token, h-half)) ---------
  {
    int lt = tid >> 1, half = tid & 1;
    int swz = (lt & 7) << 4;
    const char* xrow = (const char*)xnl + lt * 256;
    #pragma unroll
    for (int k2 = 0; k2 < 2; ++k2){
      int ee = te[k2][lt];
      int pos = gbase[ee] + tlp[k2][lt];
      if (half == 0){
        list[ee * N_TOK + pos] = tok0 + lt;
        score[ee * N_TOK + pos] = tsc[k2][lt];
      }
      const float* g1r = g1s + ee * H + half * 64;
      const float* b1r = b1s + ee * H + half * 64;
      unsigned short* dst = a1buf + ((size_t)ee * N_TOK + pos) * H + half * 64;
      #pragma unroll
      for (int hc = 0; hc < 64; hc += 8){
        short8 xv = *(const short8*)(xrow + (((half * 64 + hc) * 2) ^ swz));
        float4 ga = *(const float4*)(g1r + hc), gb4 = *(const float4*)(g1r + hc + 4);
        float4 ba = *(const float4*)(b1r + hc), bb4 = *(const float4*)(b1r + hc + 4);
        float q[8];
        #pragma unroll
        for (int j = 0; j < 8; ++j){
          float gg = j < 4 ? ga[j] : gb4[j - 4];
          float bb_ = j < 4 ? ba[j] : bb4[j - 4];
          q[j] = gelu_fast(__builtin_fmaf(bf2f((unsigned short)xv[j]), gg, bb_));
        }
        u32x4 vw;
        vw[0] = cvtpk(q[0], q[1]); vw[1] = cvtpk(q[2], q[3]);
        vw[2] = cvtpk(q[4], q[5]); vw[3] = cvtpk(q[6], q[7]);
        *(u32x4*)(dst + hc) = vw;
      }
    }
  }
}

// ---------------- Kernel MLP: 4 waves = 32 tokens, 2 barriers ---------------
// Phase-1 hoisted into the gate (a1buf). b1f = 8 coalesced 16B global loads
// (slot-indexed, no list lookup). Padded slots read garbage a1 but MFMA
// columns/rows are independent and the epilogue skips s>=ne rows.
__global__ __launch_bounds__(256, 2) void k_mlp(
    const unsigned short* __restrict__ a1buf,
    const unsigned short* __restrict__ w1p,
    const float* __restrict__ ln2g, const float* __restrict__ ln2b,
    const unsigned short* __restrict__ w2p, const float* __restrict__ b2,
    const int* __restrict__ cnt, const int* __restrict__ list,
    const float* __restrict__ score, float* __restrict__ out){
  __shared__ __align__(16) unsigned short tls[2][16 * I_DIM];  // 32 KB
  __shared__ float2 psum[4][2][16];                            // 1 KB
  __shared__ __align__(16) float pg2[I_DIM], pb2[I_DIM];       // 4 KB
  __shared__ float pbb[H];                                     // 0.5 KB

  int tid = threadIdx.x, wv = tid >> 6, lane = tid & 63;
  int slot0 = blockIdx.x * 32;
  int base, ne;
  int e = slot_to_expert(cnt, slot0, base, ne);
  if (e < 0 || base >= ne) return;
  const int l15 = lane & 15, l4 = lane >> 4;

  // stage per-expert LN2/bias params
  pg2[tid]       = ln2g[e * I_DIM + tid];
  pg2[tid + 256] = ln2g[e * I_DIM + tid + 256];
  pb2[tid]       = ln2b[e * I_DIM + tid];
  pb2[tid + 256] = ln2b[e * I_DIM + tid + 256];
  if (tid < H) pbb[tid] = b2[e * H + tid];

  // ---- b1f direct from a1buf (B-frag: token=l15 of tile tl, h=kt*32+l4*8+j)
  short8 b1f[4][2];
  #pragma unroll
  for (int tl = 0; tl < 2; ++tl){
    const unsigned short* ar = a1buf + ((size_t)e * N_TOK + base + tl * 16 + l15) * H;
    #pragma unroll
    for (int kt = 0; kt < 4; ++kt)
      b1f[kt][tl] = *(const short8*)(ar + kt * 32 + l4 * 8);
  }

  // ---- phase 2: GEMM1, wave's 8 i-tiles -----------------------------------
  const unsigned short* w1e = w1p + ((size_t)e << 16);
  float Sx[2] = {0.f, 0.f}, Qx[2] = {0.f, 0.f};

  short8 afA[4], afB[4];
  {
    int it = wv * 8;
    #pragma unroll
    for (int kt = 0; kt < 4; ++kt)
      afA[kt] = *(const short8*)(w1e + (size_t)(((it << 2) | kt) << 9) + lane * 8);
  }
  #pragma unroll
  for (int ii = 0; ii < 8; ++ii){
    int it = wv * 8 + ii;
    if (ii < 7){
      int itn = it + 1;
      #pragma unroll
      for (int kt = 0; kt < 4; ++kt)
        afB[kt] = *(const short8*)(w1e + (size_t)(((itn << 2) | kt) << 9) + lane * 8);
    }
    __builtin_amdgcn_sched_barrier(0);
    f32x4 acc[2];
    #pragma unroll
    for (int tl = 0; tl < 2; ++tl){ f32x4 z = {0.f,0.f,0.f,0.f}; acc[tl] = z; }
    __builtin_amdgcn_s_setprio(1);
    #pragma unroll
    for (int kt = 0; kt < 4; ++kt)
      #pragma unroll
      for (int tl = 0; tl < 2; ++tl)
        acc[tl] = mfma16(afA[kt], b1f[kt][tl], acc[tl]);
    __builtin_amdgcn_s_setprio(0);

    int kt2 = it >> 1;
    int lh = (it * 2 + (l4 >> 1)) & 3;
    int off = ((kt2 * 4 + lh) * 16 + l15) * 8 + (l4 & 1) * 4;  // u16 units
    #pragma unroll
    for (int tl = 0; tl < 2; ++tl){
      #pragma unroll
      for (int r = 0; r < 4; ++r){
        float v = acc[tl][r];
        Sx[tl] += v; Qx[tl] = __builtin_fmaf(v, v, Qx[tl]);
      }
      u32x2 w0;
      w0[0] = cvtpk(acc[tl][0], acc[tl][1]);
      w0[1] = cvtpk(acc[tl][2], acc[tl][3]);
      *(u32x2*)((char*)&tls[tl][0] + (size_t)off * 2) = w0;
    }
    #pragma unroll
    for (int kt = 0; kt < 4; ++kt) afA[kt] = afB[kt];
  }

  #pragma unroll
  for (int tl = 0; tl < 2; ++tl){
    Sx[tl] += __shfl_xor(Sx[tl], 16);  Qx[tl] += __shfl_xor(Qx[tl], 16);
    Sx[tl] += __shfl_xor(Sx[tl], 32);  Qx[tl] += __shfl_xor(Qx[tl], 32);
  }
  if (l4 == 0){
    #pragma unroll
    for (int tl = 0; tl < 2; ++tl)
      psum[wv][tl][l15] = make_float2(Sx[tl], Qx[tl]);
  }
  __syncthreads();

  // ---- phase 3: LN2 + gelu in-place; wave owns (tile wv&1, kt-half wv>>1) -
  {
    int tl3 = wv & 1, ktb = (wv >> 1) * 8;
    float S = 0.f, Q = 0.f;
    #pragma unroll
    for (int w4 = 0; w4 < 4; ++w4){
      float2 p = psum[w4][tl3][l15];
      S += p.x; Q += p.y;
    }
    float mu = S * (1.f / I_DIM);
    float var = __builtin_fmaf(Q, 1.f / I_DIM, -mu * mu);
    float rsig = rsqrtf(fmaxf(var, 0.f) + EPS);
    float mrs = mu * rsig;

    unsigned short* ta = &tls[tl3][0];
    #pragma unroll
    for (int k2 = 0; k2 < 8; ++k2){
      int kt = ktb + k2;
      int i0 = kt * 32 + l4 * 8;
      float4 g2a = *(const float4*)(pg2 + i0), g2b = *(const float4*)(pg2 + i0 + 4);
      float4 b2a = *(const float4*)(pb2 + i0), b2b = *(const float4*)(pb2 + i0 + 4);
      short8 tv = *(const short8*)((const char*)ta + (size_t)(kt * 64 + lane) * 16);
      float q[8];
      #pragma unroll
      for (int j = 0; j < 8; ++j){
        float gg = j < 4 ? g2a[j] : g2b[j - 4];
        float bb_ = j < 4 ? b2a[j] : b2b[j - 4];
        float v0 = __builtin_fmaf(bf2f((unsigned short)tv[j]), rsig, -mrs);
        q[j] = gelu_fast(__builtin_fmaf(v0, gg, bb_));
      }
      u32x4 vw;
      vw[0] = cvtpk(q[0], q[1]); vw[1] = cvtpk(q[2], q[3]);
      vw[2] = cvtpk(q[4], q[5]); vw[3] = cvtpk(q[6], q[7]);
      *(u32x4*)((char*)ta + (size_t)(kt * 64 + lane) * 16) = vw;
    }
  }
  __syncthreads();

  // ---- phase 4: GEMM2, wave's 2 h-tiles -----------------------------------
  const unsigned short* w2e = w2p + ((size_t)e << 16);
  f32x4 c[2][2];   // [hh][tl]
  #pragma unroll
  for (int hh = 0; hh < 2; ++hh)
    #pragma unroll
    for (int tl = 0; tl < 2; ++tl){ f32x4 z = {0.f,0.f,0.f,0.f}; c[hh][tl] = z; }

  short8 awA[2], awB[2], fA[2], fB[2];
  {
    #pragma unroll
    for (int hh = 0; hh < 2; ++hh){
      int h = wv * 2 + hh;
      awA[hh] = *(const short8*)(w2e + (size_t)(((h << 4) | 0) << 9) + lane * 8);
    }
    #pragma unroll
    for (int tl = 0; tl < 2; ++tl)
      fA[tl] = *(const short8*)((const char*)&tls[tl][0] + (size_t)(0 * 64 + lane) * 16);
  }
  #pragma unroll
  for (int kt = 0; kt < 16; ++kt){
    if (kt < 15){
      int ktn = kt + 1;
      #pragma unroll
      for (int hh = 0; hh < 2; ++hh){
        int h = wv * 2 + hh;
        awB[hh] = *(const short8*)(w2e + (size_t)(((h << 4) | ktn) << 9) + lane * 8);
      }
      #pragma unroll
      for (int tl = 0; tl < 2; ++tl)
        fB[tl] = *(const short8*)((const char*)&tls[tl][0] + (size_t)(ktn * 64 + lane) * 16);
    }
    __builtin_amdgcn_sched_barrier(0);
    __builtin_amdgcn_s_setprio(1);
    #pragma unroll
    for (int tl = 0; tl < 2; ++tl){
      c[0][tl] = mfma16(fA[tl], awA[0], c[0][tl]);
      c[1][tl] = mfma16(fA[tl], awA[1], c[1][tl]);
    }
    __builtin_amdgcn_s_setprio(0);
    #pragma unroll
    for (int hh = 0; hh < 2; ++hh) awA[hh] = awB[hh];
    #pragma unroll
    for (int tl = 0; tl < 2; ++tl) fA[tl] = fB[tl];
  }

  // ---- epilogue: token = base+tl*16+l4*4+r, h = (wv*2+hh)*16 + l15 --------
  float bb[2];
  #pragma unroll
  for (int hh = 0; hh < 2; ++hh) bb[hh] = pbb[(wv * 2 + hh) * 16 + l15];

  #pragma unroll
  for (int tl = 0; tl < 2; ++tl){
    #pragma unroll
    for (int r = 0; r < 4; ++r){
      int s = base + tl * 16 + l4 * 4 + r;
      if (s < ne){
        int tok = list[e * N_TOK + s];
        float sc = score[e * N_TOK + s];
        float* orow = out + (size_t)tok * H + l15;
        #pragma unroll
        for (int hh = 0; hh < 2; ++hh)
          atomicAdd(orow + (wv * 2 + hh) * 16, (c[hh][tl][r] + bb[hh]) * sc);
      }
    }
  }
}

extern "C" void kernel_launch(void* const* d_in, const int* in_sizes, int n_in,
                              void* d_out, int out_size, void* d_ws, size_t ws_size,
                              hipStream_t stream){
  const float* x     = (const float*)d_in[0];
  const float* gw    = (const float*)d_in[1];
  const float* gb    = (const float*)d_in[2];
  const float* ln1g  = (const float*)d_in[3];
  const float* ln1b  = (const float*)d_in[4];
  const float* w1    = (const float*)d_in[5];
  const float* ln2g  = (const float*)d_in[6];
  const float* ln2b  = (const float*)d_in[7];
  const float* w2    = (const float*)d_in[8];
  const float* b2    = (const float*)d_in[9];
  float* out = (float*)d_out;

  char* w = (char*)d_ws;
  unsigned short* a1buf = (unsigned short*)w;  w += ((size_t)E * N_TOK + 64) * H * 2; // 67.1 MB
  unsigned short* w1p = (unsigned short*)w;    w += (size_t)E * I_DIM * H * 2;        // 1.05 MB
  unsigned short* w2p = (unsigned short*)w;    w += (size_t)E * H * I_DIM * 2;        // 1.05 MB
  int*    list  = (int*)w;                     w += (size_t)E * N_TOK * 4;            // 1.05 MB
  float*  score = (float*)w;                   w += (size_t)E * N_TOK * 4;            // 1.05 MB
  int*    cnt   = (int*)w;                     w += 256;

  (void)hipMemsetAsync(cnt, 0, 256, stream);

  k_front<<<dim3(1024), dim3(256), 0, stream>>>(
      w1, w2, w1p, w2p, x, gw, gb, ln1g, ln1b, a1buf, cnt, list, score, out);
  k_mlp<<<dim3(NSLOT_MAX / 32), dim3(256), 0, stream>>>(
      a1buf, w1p, ln2g, ln2b, w2p, b2, cnt, list, score, out);
}

// Round 19
// 74.772 us; speedup vs baseline: 1.0402x; 1.0402x over previous
//
#include <hip/hip_runtime.h>
#include <hip/hip_bf16.h>

#define N_TOK 32768
#define H 128
#define I_DIM 512
#define E 8
#define EPS 1e-5f
#define GATE_TPB 64
#define NSLOT_MAX (N_TOK * 2 + E * 32)   // 32-padded slot capacity (65792)

typedef __attribute__((ext_vector_type(8))) short short8;
typedef __attribute__((ext_vector_type(4))) float f32x4;
typedef __attribute__((ext_vector_type(2))) unsigned int u32x2;
typedef __attribute__((ext_vector_type(4))) unsigned int u32x4;
typedef __attribute__((ext_vector_type(8))) __bf16 bf16x8;

__device__ inline unsigned short f2bf(float f){
  unsigned int u = __builtin_bit_cast(unsigned int, f);
  u += 0x7fffu + ((u >> 16) & 1u);
  return (unsigned short)(u >> 16);
}
__device__ inline float bf2f(unsigned short s){
  unsigned int u = ((unsigned int)s) << 16;
  return __builtin_bit_cast(float, u);
}
// Packed f32->bf16 (RNE) via HIP intrinsic; byte-copy out.
__device__ inline unsigned int cvtpk(float lo, float hi){
  __hip_bfloat162 h = __float22bfloat162_rn(make_float2(lo, hi));
  unsigned int r;
  __builtin_memcpy(&r, &h, 4);
  return r;
}
// fast GELU (tanh form), |err| <= ~3e-4 vs exact erf-GELU
__device__ inline float gelu_fast(float x){
  const float A = 0.10294517f;
  const float B = 2.30214175f;
  float x2 = x * x;
  float v  = __builtin_fmaf(x2, A, B);
  float z  = __builtin_amdgcn_exp2f(v * x);
  float r  = __builtin_amdgcn_rcpf(z + 1.f);
  return __builtin_fmaf(-x, r, x);
}
__device__ inline f32x4 mfma16(short8 a, short8 b, f32x4 c){
  return __builtin_amdgcn_mfma_f32_16x16x32_bf16(
      __builtin_bit_cast(bf16x8, a), __builtin_bit_cast(bf16x8, b), c, 0, 0, 0);
}

// Dense 32-padded slot-space -> (expert, base, ne).
__device__ inline int slot_to_expert(const int* __restrict__ cnt, int slot0,
                                     int& base, int& ne){
  int e = -1, p = 0;
  #pragma unroll
  for (int q = 0; q < E; ++q){
    int c = cnt[q];
    int pc = (c + 31) & ~31;
    if (slot0 >= p && slot0 < p + pc){ e = q; base = slot0 - p; ne = c; }
    p += pc;
  }
  return e;
}

// ---- Kernel FRONT: prep (blk 0-255) | gate (256-767) | zero (768-1279) ----
// GATE_TPB=64: gate's serial per-wave iteration count halves (2 vs 4), so the
// gate long-pole block is ~half as long; same total gate work across 2x blocks.
__global__ __launch_bounds__(256) void k_front(
    const float* __restrict__ w1, const float* __restrict__ w2,
    unsigned short* __restrict__ w1p, unsigned short* __restrict__ w2p,
    const float* __restrict__ x, const float* __restrict__ gw,
    const float* __restrict__ gb, unsigned short* __restrict__ xn,
    int* __restrict__ cnt, int* __restrict__ list, float* __restrict__ score,
    float* __restrict__ out){
  __shared__ __align__(16) float gws[E * H];
  __shared__ float gbs[E];
  __shared__ int   lcnt[E];
  __shared__ int   gbase[E];
  __shared__ int   te[2][GATE_TPB];
  __shared__ float tsc[2][GATE_TPB];
  __shared__ int   tlp[2][GATE_TPB];

  int tid = threadIdx.x;
  int blk = blockIdx.x;

  if (blk >= 768){
    float4 z = {0.f, 0.f, 0.f, 0.f};
    float4* o4 = (float4*)out;
    int base4 = (blk - 768) * 2048 + tid;
    #pragma unroll
    for (int q = 0; q < 8; ++q) o4[base4 + q * 256] = z;
    return;
  }

  if (blk < 256){
    int q = blk * 256 + tid;
    int e = q >> 13, rem = q & 8191;
    {
      int it = rem >> 8, kt = (rem >> 6) & 3, l = rem & 63;
      int row = it * 16 + (l & 15), h0 = kt * 32 + (l >> 4) * 8;
      const float* src = w1 + ((size_t)(e * 512 + row) * 128 + h0);
      float4 v0 = *(const float4*)src, v1 = *(const float4*)(src + 4);
      short8 o;
      #pragma unroll
      for (int j = 0; j < 4; ++j){ o[j] = (short)f2bf(v0[j]); o[j+4] = (short)f2bf(v1[j]); }
      *(short8*)(w1p + (size_t)q * 8) = o;
    }
    {
      int ht = rem >> 10, kt = (rem >> 6) & 15, l = rem & 63;
      int row = ht * 16 + (l & 15), i0 = kt * 32 + (l >> 4) * 8;
      const float* src = w2 + ((size_t)(e * 128 + row) * 512 + i0);
      float4 v0 = *(const float4*)src, v1 = *(const float4*)(src + 4);
      short8 o;
      #pragma unroll
      for (int j = 0; j < 4; ++j){ o[j] = (short)f2bf(v0[j]); o[j+4] = (short)f2bf(v1[j]); }
      *(short8*)(w2p + (size_t)q * 8) = o;
    }
    return;
  }

  // ---- gate ----
  for (int i = tid; i < E * H; i += 256) gws[i] = gw[i];
  if (tid < E){ gbs[tid] = gb[tid]; lcnt[tid] = 0; }
  __syncthreads();

  int wave = tid >> 6, lane = tid & 63;
  int g = lane >> 3, c8 = lane & 7;
  int tok0 = (blk - 256) * GATE_TPB;
  const float4* gws4 = (const float4*)gws;

  for (int t = 0; t < GATE_TPB / 32; ++t){
    int lt = t * 32 + wave * 8 + g;
    int tok = tok0 + lt;
    const float4* xr = (const float4*)(x + (size_t)tok * H) + c8 * 4;
    float4 v[4];
    #pragma unroll
    for (int q = 0; q < 4; ++q) v[q] = xr[q];

    float S = 0.f, Q = 0.f;
    float lg[E];
    #pragma unroll
    for (int e = 0; e < E; e++) lg[e] = 0.f;
    #pragma unroll
    for (int q = 0; q < 4; ++q){
      #pragma unroll
      for (int r = 0; r < 4; ++r){
        float f = v[q][r];
        S += f; Q = __builtin_fmaf(f, f, Q);
      }
      #pragma unroll
      for (int e = 0; e < E; e++){
        float4 wv = gws4[e * 32 + c8 * 4 + q];
        #pragma unroll
        for (int r = 0; r < 4; ++r) lg[e] = __builtin_fmaf(v[q][r], wv[r], lg[e]);
      }
    }
    #pragma unroll
    for (int m = 1; m < 8; m <<= 1){
      S += __shfl_xor(S, m);
      Q += __shfl_xor(Q, m);
      #pragma unroll
      for (int e = 0; e < E; e++) lg[e] += __shfl_xor(lg[e], m);
    }

    float mu = S * (1.f / H);
    float var = Q * (1.f / H) - mu * mu;
    float rsig = rsqrtf(fmaxf(var, 0.f) + EPS);

    short8 s0, s1;
    #pragma unroll
    for (int r = 0; r < 4; ++r){
      s0[r]     = (short)f2bf((v[0][r] - mu) * rsig);
      s0[r + 4] = (short)f2bf((v[1][r] - mu) * rsig);
      s1[r]     = (short)f2bf((v[2][r] - mu) * rsig);
      s1[r + 4] = (short)f2bf((v[3][r] - mu) * rsig);
    }
    unsigned short* xo = xn + (size_t)tok * H + c8 * 16;
    *(short8*)xo = s0;
    *(short8*)(xo + 8) = s1;

    if (c8 == 0){
      float mx = -1e30f;
      #pragma unroll
      for (int e = 0; e < E; e++){ lg[e] += gbs[e]; mx = fmaxf(mx, lg[e]); }
      float p[E], sum = 0.f;
      #pragma unroll
      for (int e = 0; e < E; e++){ p[e] = __expf(lg[e] - mx); sum += p[e]; }
      float inv = 1.f / sum;
      int e0 = 0; float p0 = p[0];
      #pragma unroll
      for (int e = 1; e < E; e++) if (p[e] > p0){ e0 = e; p0 = p[e]; }
      int e1 = -1; float p1 = -1.f;
      #pragma unroll
      for (int e = 0; e < E; e++) if (e != e0 && p[e] > p1){ e1 = e; p1 = p[e]; }
      te[0][lt] = e0; tsc[0][lt] = p0 * inv; tlp[0][lt] = atomicAdd(&lcnt[e0], 1);
      te[1][lt] = e1; tsc[1][lt] = p1 * inv; tlp[1][lt] = atomicAdd(&lcnt[e1], 1);
    }
  }
  __syncthreads();
  if (tid < E) gbase[tid] = atomicAdd(&cnt[tid], lcnt[tid]);
  __syncthreads();
  if (tid < GATE_TPB){
    int tok = tok0 + tid;
    #pragma unroll
    for (int k2 = 0; k2 < 2; k2++){
      int ee = te[k2][tid];
      int pos = gbase[ee] + tlp[k2][tid];
      list[ee * N_TOK + pos] = tok;
      score[ee * N_TOK + pos] = tsc[k2][tid];
    }
  }
}

// ---------------- Kernel MLP: 4 waves = 32 tokens, 38KB LDS (r17) -----------
__global__ __launch_bounds__(256, 2) void k_mlp(
    const unsigned short* __restrict__ xn,
    const float* __restrict__ ln1g, const float* __restrict__ ln1b,
    const unsigned short* __restrict__ w1p,
    const float* __restrict__ ln2g, const float* __restrict__ ln2b,
    const unsigned short* __restrict__ w2p, const float* __restrict__ b2,
    const int* __restrict__ cnt, const int* __restrict__ list,
    const float* __restrict__ score, float* __restrict__ out){
  __shared__ __align__(16) unsigned short tls[2][16 * I_DIM];  // 32 KB
  __shared__ float2 psum[4][2][16];                            // 1 KB
  __shared__ __align__(16) float pg2[I_DIM], pb2[I_DIM];       // 4 KB
  __shared__ float pbb[H];                                     // 0.5 KB

  int tid = threadIdx.x, wv = tid >> 6, lane = tid & 63;
  int slot0 = blockIdx.x * 32;
  int base, ne;
  int e = slot_to_expert(cnt, slot0, base, ne);
  if (e < 0 || base >= ne) return;
  const int l15 = lane & 15, l4 = lane >> 4;

  // stage per-expert LN2/bias params
  pg2[tid]       = ln2g[e * I_DIM + tid];
  pg2[tid + 256] = ln2g[e * I_DIM + tid + 256];
  pb2[tid]       = ln2b[e * I_DIM + tid];
  pb2[tid + 256] = ln2b[e * I_DIM + tid + 256];
  if (tid < H) pbb[tid] = b2[e * H + tid];

  // ---- phase 1: compute 2/8 b1f combos, stash in overlay (tls[0]) ---------
  {
    const float* g1e = ln1g + e * H;
    const float* b1e = ln1b + e * H;
    #pragma unroll
    for (int c2 = 0; c2 < 2; ++c2){
      int combo = wv * 2 + c2;            // 0..7 = kt*2 + tl
      int kt = combo >> 1, tl = combo & 1;
      int h0 = kt * 32 + l4 * 8;
      int s = base + tl * 16 + l15;
      int tok = s < ne ? list[e * N_TOK + s] : 0;
      short8 xv = *(const short8*)(xn + (size_t)tok * H + h0);
      float4 ga = *(const float4*)(g1e + h0), gbv = *(const float4*)(g1e + h0 + 4);
      float4 ba = *(const float4*)(b1e + h0), bbv = *(const float4*)(b1e + h0 + 4);
      float q[8];
      #pragma unroll
      for (int j = 0; j < 8; ++j){
        float f = bf2f((unsigned short)xv[j]);
        float gg = j < 4 ? ga[j] : gbv[j - 4];
        float bb_ = j < 4 ? ba[j] : bbv[j - 4];
        q[j] = gelu_fast(__builtin_fmaf(f, gg, bb_));
      }
      u32x4 vw;
      vw[0] = cvtpk(q[0], q[1]); vw[1] = cvtpk(q[2], q[3]);
      vw[2] = cvtpk(q[4], q[5]); vw[3] = cvtpk(q[6], q[7]);
      *(u32x4*)((char*)&tls[0][0] + (size_t)((combo * 64 + lane) << 4)) = vw;
    }
  }
  __syncthreads();
  short8 b1f[4][2];
  #pragma unroll
  for (int kt = 0; kt < 4; ++kt)
    #pragma unroll
    for (int tl = 0; tl < 2; ++tl)
      b1f[kt][tl] = *(const short8*)((const char*)&tls[0][0] +
                                     (size_t)(((kt * 2 + tl) * 64 + lane) << 4));
  __syncthreads();

  // ---- phase 2: GEMM1, wave's 8 i-tiles -----------------------------------
  const unsigned short* w1e = w1p + ((size_t)e << 16);
  float Sx[2] = {0.f, 0.f}, Qx[2] = {0.f, 0.f};

  short8 afA[4], afB[4];
  {
    int it = wv * 8;
    #pragma unroll
    for (int kt = 0; kt < 4; ++kt)
      afA[kt] = *(const short8*)(w1e + (size_t)(((it << 2) | kt) << 9) + lane * 8);
  }
  #pragma unroll
  for (int ii = 0; ii < 8; ++ii){
    int it = wv * 8 + ii;
    if (ii < 7){
      int itn = it + 1;
      #pragma unroll
      for (int kt = 0; kt < 4; ++kt)
        afB[kt] = *(const short8*)(w1e + (size_t)(((itn << 2) | kt) << 9) + lane * 8);
    }
    __builtin_amdgcn_sched_barrier(0);
    f32x4 acc[2];
    #pragma unroll
    for (int tl = 0; tl < 2; ++tl){ f32x4 z = {0.f,0.f,0.f,0.f}; acc[tl] = z; }
    __builtin_amdgcn_s_setprio(1);
    #pragma unroll
    for (int kt = 0; kt < 4; ++kt)
      #pragma unroll
      for (int tl = 0; tl < 2; ++tl)
        acc[tl] = mfma16(afA[kt], b1f[kt][tl], acc[tl]);
    __builtin_amdgcn_s_setprio(0);

    int kt2 = it >> 1;
    int lh = (it * 2 + (l4 >> 1)) & 3;
    int off = ((kt2 * 4 + lh) * 16 + l15) * 8 + (l4 & 1) * 4;  // u16 units
    #pragma unroll
    for (int tl = 0; tl < 2; ++tl){
      #pragma unroll
      for (int r = 0; r < 4; ++r){
        float v = acc[tl][r];
        Sx[tl] += v; Qx[tl] = __builtin_fmaf(v, v, Qx[tl]);
      }
      u32x2 w0;
      w0[0] = cvtpk(acc[tl][0], acc[tl][1]);
      w0[1] = cvtpk(acc[tl][2], acc[tl][3]);
      *(u32x2*)((char*)&tls[tl][0] + (size_t)off * 2) = w0;
    }
    #pragma unroll
    for (int kt = 0; kt < 4; ++kt) afA[kt] = afB[kt];
  }

  #pragma unroll
  for (int tl = 0; tl < 2; ++tl){
    Sx[tl] += __shfl_xor(Sx[tl], 16);  Qx[tl] += __shfl_xor(Qx[tl], 16);
    Sx[tl] += __shfl_xor(Sx[tl], 32);  Qx[tl] += __shfl_xor(Qx[tl], 32);
  }
  if (l4 == 0){
    #pragma unroll
    for (int tl = 0; tl < 2; ++tl)
      psum[wv][tl][l15] = make_float2(Sx[tl], Qx[tl]);
  }
  __syncthreads();

  // ---- phase 3: LN2 + gelu in-place; wave owns (tile wv&1, kt-half wv>>1) -
  {
    int tl3 = wv & 1, ktb = (wv >> 1) * 8;
    float S = 0.f, Q = 0.f;
    #pragma unroll
    for (int w4 = 0; w4 < 4; ++w4){
      float2 p = psum[w4][tl3][l15];
      S += p.x; Q += p.y;
    }
    float mu = S * (1.f / I_DIM);
    float var = __builtin_fmaf(Q, 1.f / I_DIM, -mu * mu);
    float rsig = rsqrtf(fmaxf(var, 0.f) + EPS);
    float mrs = mu * rsig;

    unsigned short* ta = &tls[tl3][0];
    #pragma unroll
    for (int k2 = 0; k2 < 8; ++k2){
      int kt = ktb + k2;
      int i0 = kt * 32 + l4 * 8;
      float4 g2a = *(const float4*)(pg2 + i0), g2b = *(const float4*)(pg2 + i0 + 4);
      float4 b2a = *(const float4*)(pb2 + i0), b2b = *(const float4*)(pb2 + i0 + 4);
      short8 tv = *(const short8*)((const char*)ta + (size_t)(kt * 64 + lane) * 16);
      float q[8];
      #pragma unroll
      for (int j = 0; j < 8; ++j){
        float gg = j < 4 ? g2a[j] : g2b[j - 4];
        float bb_ = j < 4 ? b2a[j] : b2b[j - 4];
        float v0 = __builtin_fmaf(bf2f((unsigned short)tv[j]), rsig, -mrs);
        q[j] = gelu_fast(__builtin_fmaf(v0, gg, bb_));
      }
      u32x4 vw;
      vw[0] = cvtpk(q[0], q[1]); vw[1] = cvtpk(q[2], q[3]);
      vw[2] = cvtpk(q[4], q[5]); vw[3] = cvtpk(q[6], q[7]);
      *(u32x4*)((char*)ta + (size_t)(kt * 64 + lane) * 16) = vw;
    }
  }
  __syncthreads();

  // ---- phase 4: GEMM2, wave's 2 h-tiles -----------------------------------
  const unsigned short* w2e = w2p + ((size_t)e << 16);
  f32x4 c[2][2];   // [hh][tl]
  #pragma unroll
  for (int hh = 0; hh < 2; ++hh)
    #pragma unroll
    for (int tl = 0; tl < 2; ++tl){ f32x4 z = {0.f,0.f,0.f,0.f}; c[hh][tl] = z; }

  short8 awA[2], awB[2], fA[2], fB[2];
  {
    #pragma unroll
    for (int hh = 0; hh < 2; ++hh){
      int h = wv * 2 + hh;
      awA[hh] = *(const short8*)(w2e + (size_t)(((h << 4) | 0) << 9) + lane * 8);
    }
    #pragma unroll
    for (int tl = 0; tl < 2; ++tl)
      fA[tl] = *(const short8*)((const char*)&tls[tl][0] + (size_t)(0 * 64 + lane) * 16);
  }
  #pragma unroll
  for (int kt = 0; kt < 16; ++kt){
    if (kt < 15){
      int ktn = kt + 1;
      #pragma unroll
      for (int hh = 0; hh < 2; ++hh){
        int h = wv * 2 + hh;
        awB[hh] = *(const short8*)(w2e + (size_t)(((h << 4) | ktn) << 9) + lane * 8);
      }
      #pragma unroll
      for (int tl = 0; tl < 2; ++tl)
        fB[tl] = *(const short8*)((const char*)&tls[tl][0] + (size_t)(ktn * 64 + lane) * 16);
    }
    __builtin_amdgcn_sched_barrier(0);
    __builtin_amdgcn_s_setprio(1);
    #pragma unroll
    for (int tl = 0; tl < 2; ++tl){
      c[0][tl] = mfma16(fA[tl], awA[0], c[0][tl]);
      c[1][tl] = mfma16(fA[tl], awA[1], c[1][tl]);
    }
    __builtin_amdgcn_s_setprio(0);
    #pragma unroll
    for (int hh = 0; hh < 2; ++hh) awA[hh] = awB[hh];
    #pragma unroll
    for (int tl = 0; tl < 2; ++tl) fA[tl] = fB[tl];
  }

  // ---- epilogue: token = base+tl*16+l4*4+r, h = (wv*2+hh)*16 + l15 --------
  float bb[2];
  #pragma unroll
  for (int hh = 0; hh < 2; ++hh) bb[hh] = pbb[(wv * 2 + hh) * 16 + l15];

  #pragma unroll
  for (int tl = 0; tl < 2; ++tl){
    #pragma unroll
    for (int r = 0; r < 4; ++r){
      int s = base + tl * 16 + l4 * 4 + r;
      if (s < ne){
        int tok = list[e * N_TOK + s];
        float sc = score[e * N_TOK + s];
        float* orow = out + (size_t)tok * H + l15;
        #pragma unroll
        for (int hh = 0; hh < 2; ++hh)
          atomicAdd(orow + (wv * 2 + hh) * 16, (c[hh][tl][r] + bb[hh]) * sc);
      }
    }
  }
}

extern "C" void kernel_launch(void* const* d_in, const int* in_sizes, int n_in,
                              void* d_out, int out_size, void* d_ws, size_t ws_size,
                              hipStream_t stream){
  const float* x     = (const float*)d_in[0];
  const float* gw    = (const float*)d_in[1];
  const float* gb    = (const float*)d_in[2];
  const float* ln1g  = (const float*)d_in[3];
  const float* ln1b  = (const float*)d_in[4];
  const float* w1    = (const float*)d_in[5];
  const float* ln2g  = (const float*)d_in[6];
  const float* ln2b  = (const float*)d_in[7];
  const float* w2    = (const float*)d_in[8];
  const float* b2    = (const float*)d_in[9];
  float* out = (float*)d_out;

  char* w = (char*)d_ws;
  unsigned short* xn  = (unsigned short*)w;  w += (size_t)N_TOK * H * 2;
  unsigned short* w1p = (unsigned short*)w;  w += (size_t)E * I_DIM * H * 2;
  unsigned short* w2p = (unsigned short*)w;  w += (size_t)E * H * I_DIM * 2;
  int*    list  = (int*)w;                   w += (size_t)E * N_TOK * 4;
  float*  score = (float*)w;                 w += (size_t)E * N_TOK * 4;
  int*    cnt   = (int*)w;                   w += 256;

  (void)hipMemsetAsync(cnt, 0, 256, stream);

  // front: 256 prep + 512 gate + 512 out-zero blocks
  k_front<<<dim3(1280), dim3(256), 0, stream>>>(
      w1, w2, w1p, w2p, x, gw, gb, xn, cnt, list, score, out);
  k_mlp<<<dim3(NSLOT_MAX / 32), dim3(256), 0, stream>>>(
      xn, ln1g, ln1b, w1p, ln2g, ln2b, w2p, b2, cnt, list, score, out);
}

// Round 20
// 72.249 us; speedup vs baseline: 1.0765x; 1.0349x over previous
//
#include <hip/hip_runtime.h>
#include <hip/hip_bf16.h>

#define N_TOK 32768
#define H 128
#define I_DIM 512
#define E 8
#define EPS 1e-5f
#define GATE_TPB 128
#define NSLOT_MAX (N_TOK * 2 + E * 32)   // 32-padded slot capacity (65792)
#define MLP_BLOCKS (NSLOT_MAX / 32)      // 2056 = 8 * 257 (XCD-swizzle exact)

typedef __attribute__((ext_vector_type(8))) short short8;
typedef __attribute__((ext_vector_type(4))) float f32x4;
typedef __attribute__((ext_vector_type(2))) unsigned int u32x2;
typedef __attribute__((ext_vector_type(4))) unsigned int u32x4;
typedef __attribute__((ext_vector_type(8))) __bf16 bf16x8;

__device__ inline unsigned short f2bf(float f){
  unsigned int u = __builtin_bit_cast(unsigned int, f);
  u += 0x7fffu + ((u >> 16) & 1u);
  return (unsigned short)(u >> 16);
}
__device__ inline float bf2f(unsigned short s){
  unsigned int u = ((unsigned int)s) << 16;
  return __builtin_bit_cast(float, u);
}
// Packed f32->bf16 (RNE) via HIP intrinsic; byte-copy out.
__device__ inline unsigned int cvtpk(float lo, float hi){
  __hip_bfloat162 h = __float22bfloat162_rn(make_float2(lo, hi));
  unsigned int r;
  __builtin_memcpy(&r, &h, 4);
  return r;
}
// fast GELU (tanh form), |err| <= ~3e-4 vs exact erf-GELU
__device__ inline float gelu_fast(float x){
  const float A = 0.10294517f;
  const float B = 2.30214175f;
  float x2 = x * x;
  float v  = __builtin_fmaf(x2, A, B);
  float z  = __builtin_amdgcn_exp2f(v * x);
  float r  = __builtin_amdgcn_rcpf(z + 1.f);
  return __builtin_fmaf(-x, r, x);
}
__device__ inline f32x4 mfma16(short8 a, short8 b, f32x4 c){
  return __builtin_amdgcn_mfma_f32_16x16x32_bf16(
      __builtin_bit_cast(bf16x8, a), __builtin_bit_cast(bf16x8, b), c, 0, 0, 0);
}

// Dense 32-padded slot-space -> (expert, base, ne).
__device__ inline int slot_to_expert(const int* __restrict__ cnt, int slot0,
                                     int& base, int& ne){
  int e = -1, p = 0;
  #pragma unroll
  for (int q = 0; q < E; ++q){
    int c = cnt[q];
    int pc = (c + 31) & ~31;
    if (slot0 >= p && slot0 < p + pc){ e = q; base = slot0 - p; ne = c; }
    p += pc;
  }
  return e;
}

// ---------------- Kernel FRONT: prep (blk 0-255) | gate (256-511) | zero ----
__global__ __launch_bounds__(256) void k_front(
    const float* __restrict__ w1, const float* __restrict__ w2,
    unsigned short* __restrict__ w1p, unsigned short* __restrict__ w2p,
    const float* __restrict__ x, const float* __restrict__ gw,
    const float* __restrict__ gb, unsigned short* __restrict__ xn,
    int* __restrict__ cnt, int* __restrict__ list, float* __restrict__ score,
    float* __restrict__ out){
  __shared__ __align__(16) float gws[E * H];
  __shared__ float gbs[E];
  __shared__ int   lcnt[E];
  __shared__ int   gbase[E];
  __shared__ int   te[2][GATE_TPB];
  __shared__ float tsc[2][GATE_TPB];
  __shared__ int   tlp[2][GATE_TPB];

  int tid = threadIdx.x;
  int blk = blockIdx.x;

  if (blk >= 512){
    float4 z = {0.f, 0.f, 0.f, 0.f};
    float4* o4 = (float4*)out;
    int base4 = (blk - 512) * 2048 + tid;
    #pragma unroll
    for (int q = 0; q < 8; ++q) o4[base4 + q * 256] = z;
    return;
  }

  if (blk < 256){
    int q = blk * 256 + tid;
    int e = q >> 13, rem = q & 8191;
    {
      int it = rem >> 8, kt = (rem >> 6) & 3, l = rem & 63;
      int row = it * 16 + (l & 15), h0 = kt * 32 + (l >> 4) * 8;
      const float* src = w1 + ((size_t)(e * 512 + row) * 128 + h0);
      float4 v0 = *(const float4*)src, v1 = *(const float4*)(src + 4);
      short8 o;
      #pragma unroll
      for (int j = 0; j < 4; ++j){ o[j] = (short)f2bf(v0[j]); o[j+4] = (short)f2bf(v1[j]); }
      *(short8*)(w1p + (size_t)q * 8) = o;
    }
    {
      int ht = rem >> 10, kt = (rem >> 6) & 15, l = rem & 63;
      int row = ht * 16 + (l & 15), i0 = kt * 32 + (l >> 4) * 8;
      const float* src = w2 + ((size_t)(e * 128 + row) * 512 + i0);
      float4 v0 = *(const float4*)src, v1 = *(const float4*)(src + 4);
      short8 o;
      #pragma unroll
      for (int j = 0; j < 4; ++j){ o[j] = (short)f2bf(v0[j]); o[j+4] = (short)f2bf(v1[j]); }
      *(short8*)(w2p + (size_t)q * 8) = o;
    }
    return;
  }

  // ---- gate ----
  for (int i = tid; i < E * H; i += 256) gws[i] = gw[i];
  if (tid < E){ gbs[tid] = gb[tid]; lcnt[tid] = 0; }
  __syncthreads();

  int wave = tid >> 6, lane = tid & 63;
  int g = lane >> 3, c8 = lane & 7;
  int tok0 = (blk - 256) * GATE_TPB;
  const float4* gws4 = (const float4*)gws;

  for (int t = 0; t < 4; ++t){
    int lt = t * 32 + wave * 8 + g;
    int tok = tok0 + lt;
    const float4* xr = (const float4*)(x + (size_t)tok * H) + c8 * 4;
    float4 v[4];
    #pragma unroll
    for (int q = 0; q < 4; ++q) v[q] = xr[q];

    float S = 0.f, Q = 0.f;
    float lg[E];
    #pragma unroll
    for (int e = 0; e < E; e++) lg[e] = 0.f;
    #pragma unroll
    for (int q = 0; q < 4; ++q){
      #pragma unroll
      for (int r = 0; r < 4; ++r){
        float f = v[q][r];
        S += f; Q = __builtin_fmaf(f, f, Q);
      }
      #pragma unroll
      for (int e = 0; e < E; e++){
        float4 wv = gws4[e * 32 + c8 * 4 + q];
        #pragma unroll
        for (int r = 0; r < 4; ++r) lg[e] = __builtin_fmaf(v[q][r], wv[r], lg[e]);
      }
    }
    #pragma unroll
    for (int m = 1; m < 8; m <<= 1){
      S += __shfl_xor(S, m);
      Q += __shfl_xor(Q, m);
      #pragma unroll
      for (int e = 0; e < E; e++) lg[e] += __shfl_xor(lg[e], m);
    }

    float mu = S * (1.f / H);
    float var = Q * (1.f / H) - mu * mu;
    float rsig = rsqrtf(fmaxf(var, 0.f) + EPS);

    short8 s0, s1;
    #pragma unroll
    for (int r = 0; r < 4; ++r){
      s0[r]     = (short)f2bf((v[0][r] - mu) * rsig);
      s0[r + 4] = (short)f2bf((v[1][r] - mu) * rsig);
      s1[r]     = (short)f2bf((v[2][r] - mu) * rsig);
      s1[r + 4] = (short)f2bf((v[3][r] - mu) * rsig);
    }
    unsigned short* xo = xn + (size_t)tok * H + c8 * 16;
    *(short8*)xo = s0;
    *(short8*)(xo + 8) = s1;

    if (c8 == 0){
      float mx = -1e30f;
      #pragma unroll
      for (int e = 0; e < E; e++){ lg[e] += gbs[e]; mx = fmaxf(mx, lg[e]); }
      float p[E], sum = 0.f;
      #pragma unroll
      for (int e = 0; e < E; e++){ p[e] = __expf(lg[e] - mx); sum += p[e]; }
      float inv = 1.f / sum;
      int e0 = 0; float p0 = p[0];
      #pragma unroll
      for (int e = 1; e < E; e++) if (p[e] > p0){ e0 = e; p0 = p[e]; }
      int e1 = -1; float p1 = -1.f;
      #pragma unroll
      for (int e = 0; e < E; e++) if (e != e0 && p[e] > p1){ e1 = e; p1 = p[e]; }
      te[0][lt] = e0; tsc[0][lt] = p0 * inv; tlp[0][lt] = atomicAdd(&lcnt[e0], 1);
      te[1][lt] = e1; tsc[1][lt] = p1 * inv; tlp[1][lt] = atomicAdd(&lcnt[e1], 1);
    }
  }
  __syncthreads();
  if (tid < E) gbase[tid] = atomicAdd(&cnt[tid], lcnt[tid]);
  __syncthreads();
  if (tid < GATE_TPB){
    int tok = tok0 + tid;
    #pragma unroll
    for (int k2 = 0; k2 < 2; k2++){
      int ee = te[k2][tid];
      int pos = gbase[ee] + tlp[k2][tid];
      list[ee * N_TOK + pos] = tok;
      score[ee * N_TOK + pos] = tsc[k2][tid];
    }
  }
}

// ---------------- Kernel MLP: 4 waves = 32 tokens, 38KB LDS + XCD swizzle ---
// r17 structure + T1 XCD-chunked blockIdx swizzle: grid 2056 = 8*257 exactly,
// so wid = (bid%8)*257 + bid/8 is bijective. Same-expert blocks (contiguous
// slot ranges) now cluster on one XCD -> weight fragment reads hit the local
// L2 (~200cy) instead of L3 (~600cy). Tests whether the ~31us non-VALU time
// is weight-fetch latency.
__global__ __launch_bounds__(256, 2) void k_mlp(
    const unsigned short* __restrict__ xn,
    const float* __restrict__ ln1g, const float* __restrict__ ln1b,
    const unsigned short* __restrict__ w1p,
    const float* __restrict__ ln2g, const float* __restrict__ ln2b,
    const unsigned short* __restrict__ w2p, const float* __restrict__ b2,
    const int* __restrict__ cnt, const int* __restrict__ list,
    const float* __restrict__ score, float* __restrict__ out){
  __shared__ __align__(16) unsigned short tls[2][16 * I_DIM];  // 32 KB
  __shared__ float2 psum[4][2][16];                            // 1 KB
  __shared__ __align__(16) float pg2[I_DIM], pb2[I_DIM];       // 4 KB
  __shared__ float pbb[H];                                     // 0.5 KB

  int tid = threadIdx.x, wv = tid >> 6, lane = tid & 63;
  int bid = blockIdx.x;
  int wid = (bid & 7) * (MLP_BLOCKS / 8) + (bid >> 3);   // XCD-chunked swizzle
  int slot0 = wid * 32;
  int base, ne;
  int e = slot_to_expert(cnt, slot0, base, ne);
  if (e < 0 || base >= ne) return;
  const int l15 = lane & 15, l4 = lane >> 4;

  // stage per-expert LN2/bias params
  pg2[tid]       = ln2g[e * I_DIM + tid];
  pg2[tid + 256] = ln2g[e * I_DIM + tid + 256];
  pb2[tid]       = ln2b[e * I_DIM + tid];
  pb2[tid + 256] = ln2b[e * I_DIM + tid + 256];
  if (tid < H) pbb[tid] = b2[e * H + tid];

  // ---- phase 1: compute 2/8 b1f combos, stash in overlay (tls[0]) ---------
  {
    const float* g1e = ln1g + e * H;
    const float* b1e = ln1b + e * H;
    #pragma unroll
    for (int c2 = 0; c2 < 2; ++c2){
      int combo = wv * 2 + c2;            // 0..7 = kt*2 + tl
      int kt = combo >> 1, tl = combo & 1;
      int h0 = kt * 32 + l4 * 8;
      int s = base + tl * 16 + l15;
      int tok = s < ne ? list[e * N_TOK + s] : 0;
      short8 xv = *(const short8*)(xn + (size_t)tok * H + h0);
      float4 ga = *(const float4*)(g1e + h0), gbv = *(const float4*)(g1e + h0 + 4);
      float4 ba = *(const float4*)(b1e + h0), bbv = *(const float4*)(b1e + h0 + 4);
      float q[8];
      #pragma unroll
      for (int j = 0; j < 8; ++j){
        float f = bf2f((unsigned short)xv[j]);
        float gg = j < 4 ? ga[j] : gbv[j - 4];
        float bb_ = j < 4 ? ba[j] : bbv[j - 4];
        q[j] = gelu_fast(__builtin_fmaf(f, gg, bb_));
      }
      u32x4 vw;
      vw[0] = cvtpk(q[0], q[1]); vw[1] = cvtpk(q[2], q[3]);
      vw[2] = cvtpk(q[4], q[5]); vw[3] = cvtpk(q[6], q[7]);
      *(u32x4*)((char*)&tls[0][0] + (size_t)((combo * 64 + lane) << 4)) = vw;
    }
  }
  __syncthreads();
  short8 b1f[4][2];
  #pragma unroll
  for (int kt = 0; kt < 4; ++kt)
    #pragma unroll
    for (int tl = 0; tl < 2; ++tl)
      b1f[kt][tl] = *(const short8*)((const char*)&tls[0][0] +
                                     (size_t)(((kt * 2 + tl) * 64 + lane) << 4));
  __syncthreads();

  // ---- phase 2: GEMM1, wave's 8 i-tiles -----------------------------------
  const unsigned short* w1e = w1p + ((size_t)e << 16);
  float Sx[2] = {0.f, 0.f}, Qx[2] = {0.f, 0.f};

  short8 afA[4], afB[4];
  {
    int it = wv * 8;
    #pragma unroll
    for (int kt = 0; kt < 4; ++kt)
      afA[kt] = *(const short8*)(w1e + (size_t)(((it << 2) | kt) << 9) + lane * 8);
  }
  #pragma unroll
  for (int ii = 0; ii < 8; ++ii){
    int it = wv * 8 + ii;
    if (ii < 7){
      int itn = it + 1;
      #pragma unroll
      for (int kt = 0; kt < 4; ++kt)
        afB[kt] = *(const short8*)(w1e + (size_t)(((itn << 2) | kt) << 9) + lane * 8);
    }
    __builtin_amdgcn_sched_barrier(0);
    f32x4 acc[2];
    #pragma unroll
    for (int tl = 0; tl < 2; ++tl){ f32x4 z = {0.f,0.f,0.f,0.f}; acc[tl] = z; }
    __builtin_amdgcn_s_setprio(1);
    #pragma unroll
    for (int kt = 0; kt < 4; ++kt)
      #pragma unroll
      for (int tl = 0; tl < 2; ++tl)
        acc[tl] = mfma16(afA[kt], b1f[kt][tl], acc[tl]);
    __builtin_amdgcn_s_setprio(0);

    int kt2 = it >> 1;
    int lh = (it * 2 + (l4 >> 1)) & 3;
    int off = ((kt2 * 4 + lh) * 16 + l15) * 8 + (l4 & 1) * 4;  // u16 units
    #pragma unroll
    for (int tl = 0; tl < 2; ++tl){
      #pragma unroll
      for (int r = 0; r < 4; ++r){
        float v = acc[tl][r];
        Sx[tl] += v; Qx[tl] = __builtin_fmaf(v, v, Qx[tl]);
      }
      u32x2 w0;
      w0[0] = cvtpk(acc[tl][0], acc[tl][1]);
      w0[1] = cvtpk(acc[tl][2], acc[tl][3]);
      *(u32x2*)((char*)&tls[tl][0] + (size_t)off * 2) = w0;
    }
    #pragma unroll
    for (int kt = 0; kt < 4; ++kt) afA[kt] = afB[kt];
  }

  #pragma unroll
  for (int tl = 0; tl < 2; ++tl){
    Sx[tl] += __shfl_xor(Sx[tl], 16);  Qx[tl] += __shfl_xor(Qx[tl], 16);
    Sx[tl] += __shfl_xor(Sx[tl], 32);  Qx[tl] += __shfl_xor(Qx[tl], 32);
  }
  if (l4 == 0){
    #pragma unroll
    for (int tl = 0; tl < 2; ++tl)
      psum[wv][tl][l15] = make_float2(Sx[tl], Qx[tl]);
  }
  __syncthreads();

  // ---- phase 3: LN2 + gelu in-place; wave owns (tile wv&1, kt-half wv>>1) -
  {
    int tl3 = wv & 1, ktb = (wv >> 1) * 8;
    float S = 0.f, Q = 0.f;
    #pragma unroll
    for (int w4 = 0; w4 < 4; ++w4){
      float2 p = psum[w4][tl3][l15];
      S += p.x; Q += p.y;
    }
    float mu = S * (1.f / I_DIM);
    float var = __builtin_fmaf(Q, 1.f / I_DIM, -mu * mu);
    float rsig = rsqrtf(fmaxf(var, 0.f) + EPS);
    float mrs = mu * rsig;

    unsigned short* ta = &tls[tl3][0];
    #pragma unroll
    for (int k2 = 0; k2 < 8; ++k2){
      int kt = ktb + k2;
      int i0 = kt * 32 + l4 * 8;
      float4 g2a = *(const float4*)(pg2 + i0), g2b = *(const float4*)(pg2 + i0 + 4);
      float4 b2a = *(const float4*)(pb2 + i0), b2b = *(const float4*)(pb2 + i0 + 4);
      short8 tv = *(const short8*)((const char*)ta + (size_t)(kt * 64 + lane) * 16);
      float q[8];
      #pragma unroll
      for (int j = 0; j < 8; ++j){
        float gg = j < 4 ? g2a[j] : g2b[j - 4];
        float bb_ = j < 4 ? b2a[j] : b2b[j - 4];
        float v0 = __builtin_fmaf(bf2f((unsigned short)tv[j]), rsig, -mrs);
        q[j] = gelu_fast(__builtin_fmaf(v0, gg, bb_));
      }
      u32x4 vw;
      vw[0] = cvtpk(q[0], q[1]); vw[1] = cvtpk(q[2], q[3]);
      vw[2] = cvtpk(q[4], q[5]); vw[3] = cvtpk(q[6], q[7]);
      *(u32x4*)((char*)ta + (size_t)(kt * 64 + lane) * 16) = vw;
    }
  }
  __syncthreads();

  // ---- phase 4: GEMM2, wave's 2 h-tiles -----------------------------------
  const unsigned short* w2e = w2p + ((size_t)e << 16);
  f32x4 c[2][2];   // [hh][tl]
  #pragma unroll
  for (int hh = 0; hh < 2; ++hh)
    #pragma unroll
    for (int tl = 0; tl < 2; ++tl){ f32x4 z = {0.f,0.f,0.f,0.f}; c[hh][tl] = z; }

  short8 awA[2], awB[2], fA[2], fB[2];
  {
    #pragma unroll
    for (int hh = 0; hh < 2; ++hh){
      int h = wv * 2 + hh;
      awA[hh] = *(const short8*)(w2e + (size_t)(((h << 4) | 0) << 9) + lane * 8);
    }
    #pragma unroll
    for (int tl = 0; tl < 2; ++tl)
      fA[tl] = *(const short8*)((const char*)&tls[tl][0] + (size_t)(0 * 64 + lane) * 16);
  }
  #pragma unroll
  for (int kt = 0; kt < 16; ++kt){
    if (kt < 15){
      int ktn = kt + 1;
      #pragma unroll
      for (int hh = 0; hh < 2; ++hh){
        int h = wv * 2 + hh;
        awB[hh] = *(const short8*)(w2e + (size_t)(((h << 4) | ktn) << 9) + lane * 8);
      }
      #pragma unroll
      for (int tl = 0; tl < 2; ++tl)
        fB[tl] = *(const short8*)((const char*)&tls[tl][0] + (size_t)(ktn * 64 + lane) * 16);
    }
    __builtin_amdgcn_sched_barrier(0);
    __builtin_amdgcn_s_setprio(1);
    #pragma unroll
    for (int tl = 0; tl < 2; ++tl){
      c[0][tl] = mfma16(fA[tl], awA[0], c[0][tl]);
      c[1][tl] = mfma16(fA[tl], awA[1], c[1][tl]);
    }
    __builtin_amdgcn_s_setprio(0);
    #pragma unroll
    for (int hh = 0; hh < 2; ++hh) awA[hh] = awB[hh];
    #pragma unroll
    for (int tl = 0; tl < 2; ++tl) fA[tl] = fB[tl];
  }

  // ---- epilogue: token = base+tl*16+l4*4+r, h = (wv*2+hh)*16 + l15 --------
  float bb[2];
  #pragma unroll
  for (int hh = 0; hh < 2; ++hh) bb[hh] = pbb[(wv * 2 + hh) * 16 + l15];

  #pragma unroll
  for (int tl = 0; tl < 2; ++tl){
    #pragma unroll
    for (int r = 0; r < 4; ++r){
      int s = base + tl * 16 + l4 * 4 + r;
      if (s < ne){
        int tok = list[e * N_TOK + s];
        float sc = score[e * N_TOK + s];
        float* orow = out + (size_t)tok * H + l15;
        #pragma unroll
        for (int hh = 0; hh < 2; ++hh)
          atomicAdd(orow + (wv * 2 + hh) * 16, (c[hh][tl][r] + bb[hh]) * sc);
      }
    }
  }
}

extern "C" void kernel_launch(void* const* d_in, const int* in_sizes, int n_in,
                              void* d_out, int out_size, void* d_ws, size_t ws_size,
                              hipStream_t stream){
  const float* x     = (const float*)d_in[0];
  const float* gw    = (const float*)d_in[1];
  const float* gb    = (const float*)d_in[2];
  const float* ln1g  = (const float*)d_in[3];
  const float* ln1b  = (const float*)d_in[4];
  const float* w1    = (const float*)d_in[5];
  const float* ln2g  = (const float*)d_in[6];
  const float* ln2b  = (const float*)d_in[7];
  const float* w2    = (const float*)d_in[8];
  const float* b2    = (const float*)d_in[9];
  float* out = (float*)d_out;

  char* w = (char*)d_ws;
  unsigned short* xn  = (unsigned short*)w;  w += (size_t)N_TOK * H * 2;
  unsigned short* w1p = (unsigned short*)w;  w += (size_t)E * I_DIM * H * 2;
  unsigned short* w2p = (unsigned short*)w;  w += (size_t)E * H * I_DIM * 2;
  int*    list  = (int*)w;                   w += (size_t)E * N_TOK * 4;
  float*  score = (float*)w;                 w += (size_t)E * N_TOK * 4;
  int*    cnt   = (int*)w;                   w += 256;

  (void)hipMemsetAsync(cnt, 0, 256, stream);

  k_front<<<dim3(1024), dim3(256), 0, stream>>>(
      w1, w2, w1p, w2p, x, gw, gb, xn, cnt, list, score, out);
  k_mlp<<<dim3(MLP_BLOCKS), dim3(256), 0, stream>>>(
      xn, ln1g, ln1b, w1p, ln2g, ln2b, w2p, b2, cnt, list, score, out);
}